// Round 10
// baseline (25.681 us; speedup 1.0000x reference)
//
#include <hip/hip_runtime.h>
#include <math.h>

// JPEG layer: RGB->YCbCr, clip/shift, 2x2 chroma pool (sub-OFF after), 8x8 DCT,
// quantize, round. Round-10 structure: one 64-thread WG (single wave) per
// 16x16 pixel quadrant -> 4 Y + 1 Cb + 1 Cr blocks, exactly the 6 DCT blocks
// one wave handles (8 threads/block). ZERO barriers: all LDS exchange is
// intra-wave (DS ops of one wave complete in order; bit-validated rounds 7-9).
// Quant rows loaded per-lane from global (L2-hot) at wave start. 16384 small
// independent WGs de-phase naturally -> load/compute overlap across waves.

static __device__ __forceinline__ float clip01(float v) {
    return fminf(fmaxf(v, 0.0f), 1.0f);
}

// DCT-II 8x8 matrix as compile-time f32 constants: f32(0.5*cos(k*pi/16)).
// Row 0 = 1/sqrt(8), which equals M4 bitwise in f32.
#define M1f 0.49039264020161522f
#define M2f 0.46193976625564337f
#define M3f 0.41573480615127262f
#define M4f 0.35355339059327376f
#define M5f 0.27778511650980111f
#define M6f 0.19134171618254489f
#define M7f 0.097545161008064134f

static constexpr float Dm[8][8] = {
    { M4f,  M4f,  M4f,  M4f,  M4f,  M4f,  M4f,  M4f},
    { M1f,  M3f,  M5f,  M7f, -M7f, -M5f, -M3f, -M1f},
    { M2f,  M6f, -M6f, -M2f, -M2f, -M6f,  M6f,  M2f},
    { M3f, -M7f, -M1f, -M5f,  M5f,  M1f,  M7f, -M3f},
    { M4f, -M4f, -M4f,  M4f,  M4f, -M4f, -M4f,  M4f},
    { M5f, -M1f,  M7f,  M3f, -M3f, -M7f,  M1f, -M5f},
    { M6f, -M2f,  M2f, -M6f, -M6f,  M2f, -M2f,  M6f},
    { M7f, -M5f,  M3f, -M1f,  M1f, -M3f,  M5f, -M7f},
};

__global__ __launch_bounds__(64)
void jpeg_kernel(const float* __restrict__ rgb, const float* __restrict__ quant,
                 float* __restrict__ out)
{
    // wave-private LDS; integer offsets -> ds addressing
    __shared__ __align__(16) float smem[920];
    constexpr int YTT = 0;    // transposed Y quadrant [16 cols][stride 20]
    constexpr int CBT = 320;  // transposed pooled cb [8 cols][stride 12]
    constexpr int CRT = 416;  // transposed pooled cr [8 cols][stride 12]
    constexpr int TMP = 512;  // DCT temp: 6 blocks * 68 (16B-aligned, bank-spread)

    const int l  = threadIdx.x;          // 0..63
    const int wg = blockIdx.x;           // 16 b * 16 th * 16 tw * 4 quad
    const int w  = wg & 3;               // quadrant id
    const int tw = (wg >> 2) & 15;
    const int th = (wg >> 6) & 15;
    const int b  = wg >> 10;
    const int wr = w >> 1, wc = w & 1;

    const int qr = l >> 3;               // color phase: quad row 0..7
    const int qc = l & 7;                // color phase: quad col 0..7
    const int bi = l >> 3;               // DCT: block-in-wave (0..5 active)
    const int lc = l & 7;                // DCT: stage-1 col / stage-2 row

    // ---- issue rgb loads (one 2x2 quad per lane) ----
    const int prow = th * 32 + wr * 16 + 2 * qr;
    const int pcol = tw * 32 + wc * 16 + 2 * qc;
    const float* p = rgb + (size_t)b * 786432 + (size_t)prow * 512 + pcol;
    const float2 R0 = *(const float2*)p;
    const float2 R1 = *(const float2*)(p + 512);
    const float2 G0 = *(const float2*)(p + 262144);
    const float2 G1 = *(const float2*)(p + 262656);
    const float2 B0 = *(const float2*)(p + 524288);
    const float2 B1 = *(const float2*)(p + 524800);

    // ---- DCT block decode + quant-row load (issued early; L2-hot, latency
    //      hidden under the color phase) ----
    float q[8];
    int xaddr = 0; size_t obase = 0;
    if (bi < 6) {
        int ch;
        if (bi < 4) {                    // Y: 2x2 sub-blocks of the quadrant
            const int bsr = bi >> 1, bsc = bi & 1;
            xaddr = YTT + (bsc * 8 + lc) * 20 + bsr * 8; ch = 0;
            obase = (((size_t)(b * 64 + th * 4 + wr * 2 + bsr)) * 64
                     + (tw * 4 + wc * 2 + bsc)) * 64;
        } else if (bi == 4) {            // Cb: the whole pooled 8x8 quadrant
            xaddr = CBT + lc * 12; ch = 1;
            obase = (size_t)4194304
                  + (((size_t)(b * 32 + th * 2 + wr)) * 32 + (tw * 2 + wc)) * 64;
        } else {                         // Cr
            xaddr = CRT + lc * 12; ch = 2;
            obase = (size_t)5242880
                  + (((size_t)(b * 32 + th * 2 + wr)) * 32 + (tw * 2 + wc)) * 64;
        }
        const float* qp = quant + ch * 64 + lc * 8;
        *(float4*)&q[0] = *(const float4*)qp;
        *(float4*)&q[4] = *(const float4*)(qp + 4);
    }

    // ---- color transform + in-register 2x2 pooling ----
    {
        const float OFF = (float)(128.0 / 255.0);
        // order: 0=w00, 1=w01, 2=w10, 3=w11
        const float rr[4] = {R0.x, R0.y, R1.x, R1.y};
        const float gg[4] = {G0.x, G0.y, G1.x, G1.y};
        const float bb[4] = {B0.x, B0.y, B1.x, B1.y};
        float yv[4], cbv[4], crv[4];
        #pragma unroll
        for (int k = 0; k < 4; ++k) {
            const float r_ = rr[k], g_ = gg[k], b_ = bb[k];
            const float y  = (float)(0.299) * r_ + (float)(0.587) * g_ + (float)(0.114) * b_;
            const float cb = (float)(-0.168735892) * r_ + (float)(-0.331264108) * g_ + 0.5f * b_;
            const float cr = 0.5f * r_ + (float)(-0.418687589) * g_ + (float)(-0.081312411) * b_;
            yv[k]  = clip01(y) - OFF;
            cbv[k] = clip01(cb + OFF);   // clipped, pre-subtract (subtract after pool)
            crv[k] = clip01(cr + OFF);
        }
        // transposed Y writes: local col c holds Y[r][c] at YTT + c*20 + r
        *(float2*)&smem[YTT + (2 * qc) * 20 + 2 * qr]     = make_float2(yv[0], yv[2]);
        *(float2*)&smem[YTT + (2 * qc + 1) * 20 + 2 * qr] = make_float2(yv[1], yv[3]);
        // in-register pool, exact reference order ((w00+w01)+w10)+w11, then -OFF
        float sb = cbv[0];
        sb = sb + cbv[1];
        sb = sb + cbv[2];
        sb = sb + cbv[3];
        smem[CBT + qc * 12 + qr] = sb * 0.25f - OFF;
        float sr = crv[0];
        sr = sr + crv[1];
        sr = sr + crv[2];
        sr = sr + crv[3];
        smem[CRT + qc * 12 + qr] = sr * 0.25f - OFF;
    }
    // NO barrier: readers below are lanes of the SAME wave; DS ops of one wave
    // complete in order (compiler orders the RAW via lgkmcnt) — bit-validated
    // by rounds 7-9's identical no-barrier TMP round-trip.

    // ---- DCT + quantize: 8 threads per 8x8 block, one pass ----
    if (bi < 6) {
        // stage 1: thread owns column lc; column is contiguous (transposed
        // layout) -> 2x ds_read_b128. T[i] = sum_j D[i][j]*X[j][lc],
        // j-ascending fmac chain (bit-exact machinery from rounds 8-9).
        float x[8];
        *(float4*)&x[0] = *(const float4*)&smem[xaddr];
        *(float4*)&x[4] = *(const float4*)&smem[xaddr + 4];
        const int tbase = TMP + bi * 68;
        #pragma unroll
        for (int i = 0; i < 8; ++i) {
            float s = 0.0f;
            #pragma unroll
            for (int j = 0; j < 8; ++j) s += Dm[i][j] * x[j];
            smem[tbase + i * 8 + lc] = s;
        }

        // stage 2: thread owns row lc of T (intra-wave RAW, no barrier)
        float tr[8];
        *(float4*)&tr[0] = *(const float4*)&smem[tbase + lc * 8];
        *(float4*)&tr[4] = *(const float4*)&smem[tbase + lc * 8 + 4];

        const float qadd = (float)(0.5 / 255.0);
        float o[8];
        #pragma unroll
        for (int cc = 0; cc < 8; ++cc) {
            float s = 0.0f;
            #pragma unroll
            for (int k = 0; k < 8; ++k) s += tr[k] * Dm[cc][k];   // k-ascending
            // mul/add separately rounded (no FMA contraction) to match numpy
            const float den = __fadd_rn(__fmul_rn(q[cc], 2.5f), qadd);
            o[cc] = rintf(s / den);      // IEEE div + round-half-even, matches np
        }
        float* op = out + obase + lc * 8;
        *(float4*)&op[0] = make_float4(o[0], o[1], o[2], o[3]);
        *(float4*)&op[4] = make_float4(o[4], o[5], o[6], o[7]);
    }
}

extern "C" void kernel_launch(void* const* d_in, const int* in_sizes, int n_in,
                              void* d_out, int out_size, void* d_ws, size_t ws_size,
                              hipStream_t stream) {
    const float* rgb   = (const float*)d_in[0];
    const float* quant = (const float*)d_in[1];
    float* out = (float*)d_out;
    dim3 grid(16384), block(64);
    hipLaunchKernelGGL(jpeg_kernel, grid, block, 0, stream, rgb, quant, out);
}

// Round 11
// 18.779 us; speedup vs baseline: 1.3675x; 1.3675x over previous
//
#include <hip/hip_runtime.h>
#include <math.h>

// JPEG layer: RGB->YCbCr, clip/shift, 2x2 chroma pool (sub-OFF after), 8x8 DCT,
// quantize, round. Round-11: round-9 structure (256-thread WG, quad-per-thread
// color, transposed LDS tiles, 8-threads-per-block one-pass DCT) + 2-tile
// software pipeline: WG processes tiles A,B (adjacent tw). Loads B are issued
// before DCT A so 6 global loads are in flight under DCT A's ~500-cycle
// compute -> memory/compute overlap by construction. LDS double-buffered
// (21.6 KB); TMP shared between tiles (wave-private, sequential per wave).

static __device__ __forceinline__ float clip01(float v) {
    return fminf(fmaxf(v, 0.0f), 1.0f);
}

// DCT-II 8x8 matrix as compile-time f32 constants: f32(0.5*cos(k*pi/16)).
// Row 0 = 1/sqrt(8), which equals M4 bitwise in f32.
#define M1f 0.49039264020161522f
#define M2f 0.46193976625564337f
#define M3f 0.41573480615127262f
#define M4f 0.35355339059327376f
#define M5f 0.27778511650980111f
#define M6f 0.19134171618254489f
#define M7f 0.097545161008064134f

static constexpr float Dm[8][8] = {
    { M4f,  M4f,  M4f,  M4f,  M4f,  M4f,  M4f,  M4f},
    { M1f,  M3f,  M5f,  M7f, -M7f, -M5f, -M3f, -M1f},
    { M2f,  M6f, -M6f, -M2f, -M2f, -M6f,  M6f,  M2f},
    { M3f, -M7f, -M1f, -M5f,  M5f,  M1f,  M7f, -M3f},
    { M4f, -M4f, -M4f,  M4f,  M4f, -M4f, -M4f,  M4f},
    { M5f, -M1f,  M7f,  M3f, -M3f, -M7f,  M1f, -M5f},
    { M6f, -M2f,  M2f, -M6f, -M6f,  M2f, -M2f,  M6f},
    { M7f, -M5f,  M3f, -M1f,  M1f, -M3f,  M5f, -M7f},
};

struct RGB6 { float2 R0, R1, G0, G1, B0, B1; };

static __device__ __forceinline__ RGB6 load_quad(const float* __restrict__ rgb,
                                                 int b, int prow, int pcol) {
    const float* p = rgb + (size_t)b * 786432 + (size_t)prow * 512 + pcol;
    RGB6 v;
    v.R0 = *(const float2*)p;
    v.R1 = *(const float2*)(p + 512);
    v.G0 = *(const float2*)(p + 262144);
    v.G1 = *(const float2*)(p + 262656);
    v.B0 = *(const float2*)(p + 524288);
    v.B1 = *(const float2*)(p + 524800);
    return v;
}

// color transform + in-register 2x2 pool; writes transposed Y + pooled chroma.
// Arithmetic textually identical to the bit-exact round-9 kernel.
static __device__ __forceinline__ void color_store(const RGB6& v, float* smem,
    int ybase, int cbbase, int crbase, int qr, int qc)
{
    const float OFF = (float)(128.0 / 255.0);
    // order: 0=w00, 1=w01, 2=w10, 3=w11
    const float rr[4] = {v.R0.x, v.R0.y, v.R1.x, v.R1.y};
    const float gg[4] = {v.G0.x, v.G0.y, v.G1.x, v.G1.y};
    const float bb[4] = {v.B0.x, v.B0.y, v.B1.x, v.B1.y};
    float yv[4], cbv[4], crv[4];
    #pragma unroll
    for (int k = 0; k < 4; ++k) {
        const float r_ = rr[k], g_ = gg[k], b_ = bb[k];
        const float y  = (float)(0.299) * r_ + (float)(0.587) * g_ + (float)(0.114) * b_;
        const float cb = (float)(-0.168735892) * r_ + (float)(-0.331264108) * g_ + 0.5f * b_;
        const float cr = 0.5f * r_ + (float)(-0.418687589) * g_ + (float)(-0.081312411) * b_;
        yv[k]  = clip01(y) - OFF;
        cbv[k] = clip01(cb + OFF);   // clipped, pre-subtract (subtract after pool)
        crv[k] = clip01(cr + OFF);
    }
    const int r0 = 2 * qr, c0 = 2 * qc;
    // transposed Y: column c holds Y[r][c] at ybase + c*36 + r
    *(float2*)&smem[ybase + c0 * 36 + r0]       = make_float2(yv[0], yv[2]);
    *(float2*)&smem[ybase + (c0 + 1) * 36 + r0] = make_float2(yv[1], yv[3]);
    // in-register pool, exact reference order ((w00+w01)+w10)+w11, then -OFF
    float sb = cbv[0];
    sb = sb + cbv[1];
    sb = sb + cbv[2];
    sb = sb + cbv[3];
    smem[cbbase + qc * 20 + qr] = sb * 0.25f - OFF;
    float sr = crv[0];
    sr = sr + crv[1];
    sr = sr + crv[2];
    sr = sr + crv[3];
    smem[crbase + qc * 20 + qr] = sr * 0.25f - OFF;
}

// one-pass DCT for sub-block sb of a 32x32 tile (bit-exact round-8/9 machinery)
static __device__ __forceinline__ void dct_tile(float* smem, float* __restrict__ out,
    int ybase, int cbbase, int crbase, int tmpbase, const float* den,
    int b, int th, int tw, int sb, int lc)
{
    int xaddr; size_t obase;
    if (sb < 16) {               // Y: 4x4 grid of 8x8 in the 32x32 tile
        const int sr = sb >> 2, sc = sb & 3;
        xaddr = ybase + (sc * 8 + lc) * 36 + sr * 8;
        obase = (((size_t)(b * 64 + th * 4 + sr)) * 64 + (tw * 4 + sc)) * 64;
    } else if (sb < 20) {        // Cb: 2x2 grid in pooled 16x16
        const int s = sb - 16, sr = s >> 1, sc = s & 1;
        xaddr = cbbase + (sc * 8 + lc) * 20 + sr * 8;
        obase = (size_t)4194304 + (((size_t)(b * 32 + th * 2 + sr)) * 32 + (tw * 2 + sc)) * 64;
    } else {                     // Cr
        const int s = sb - 20, sr = s >> 1, sc = s & 1;
        xaddr = crbase + (sc * 8 + lc) * 20 + sr * 8;
        obase = (size_t)5242880 + (((size_t)(b * 32 + th * 2 + sr)) * 32 + (tw * 2 + sc)) * 64;
    }
    // stage 1: thread owns column lc (contiguous, transposed layout)
    float x[8];
    *(float4*)&x[0] = *(const float4*)&smem[xaddr];
    *(float4*)&x[4] = *(const float4*)&smem[xaddr + 4];
    #pragma unroll
    for (int i = 0; i < 8; ++i) {
        float s = 0.0f;
        #pragma unroll
        for (int j = 0; j < 8; ++j) s += Dm[i][j] * x[j];   // j-ascending
        smem[tmpbase + i * 8 + lc] = s;
    }
    // stage 2: thread owns row lc of T (intra-wave RAW, no barrier — validated
    // bit-exact rounds 7-10)
    float tr[8];
    *(float4*)&tr[0] = *(const float4*)&smem[tmpbase + lc * 8];
    *(float4*)&tr[4] = *(const float4*)&smem[tmpbase + lc * 8 + 4];
    float o[8];
    #pragma unroll
    for (int cc = 0; cc < 8; ++cc) {
        float s = 0.0f;
        #pragma unroll
        for (int k = 0; k < 8; ++k) s += tr[k] * Dm[cc][k]; // k-ascending
        o[cc] = rintf(s / den[cc]);  // IEEE div + round-half-even, matches np
    }
    float* op = out + obase + lc * 8;
    *(float4*)&op[0] = make_float4(o[0], o[1], o[2], o[3]);
    *(float4*)&op[4] = make_float4(o[4], o[5], o[6], o[7]);
}

__global__ __launch_bounds__(256)
void jpeg_kernel(const float* __restrict__ rgb, const float* __restrict__ quant,
                 float* __restrict__ out)
{
    // single shared block with integer offsets -> guaranteed ds addressing
    __shared__ __align__(16) float smem[5408];
    constexpr int YTT0 = 0;     // tile A transposed Y [32][36]
    constexpr int YTT1 = 1152;  // tile B transposed Y
    constexpr int CBT0 = 2304;  // tile A pooled cb [16][20]
    constexpr int CBT1 = 2624;
    constexpr int CRT0 = 2944;  // tile A pooled cr [16][20]
    constexpr int CRT1 = 3264;
    constexpr int QNT  = 3584;  // quant [3][64]
    constexpr int TMP  = 3776;  // DCT temp: 4 waves * 6 blocks * 68 (shared A/B)

    const int t = threadIdx.x;

    // stage quant into LDS (covered by the first barrier)
    if (t < 192) smem[QNT + t] = quant[t];

    // tile pair: L0 = 2*pair (even tw), L1 = L0+1 (same b, same th)
    const int pair = blockIdx.x;          // 0..2047
    const int b    = pair >> 7;
    const int rr_  = (pair << 1) & 255;
    const int th   = rr_ >> 4;
    const int twA  = rr_ & 15;
    const int twB  = twA + 1;

    const int qr = t >> 4;                // color: quad row 0..15
    const int qc = t & 15;                // color: quad col 0..15
    const int w  = t >> 6;                // wave 0..3
    const int l  = t & 63;
    const int bi = l >> 3;                // block-in-wave 0..5 (6,7 idle)
    const int lc = l & 7;                 // stage-1 col / stage-2 row
    const int sb = w * 6 + bi;            // sub-block 0..23
    const int tmpbase = TMP + w * 408 + bi * 68;

    // ---- tile A: load + color ----
    const RGB6 va = load_quad(rgb, b, th * 32 + 2 * qr, twA * 32 + 2 * qc);
    color_store(va, smem, YTT0, CBT0, CRT0, qr, qc);
    __syncthreads();

    // ---- issue tile B loads: 6 global loads in flight under DCT A ----
    const RGB6 vb = load_quad(rgb, b, th * 32 + 2 * qr, twB * 32 + 2 * qc);

    // ---- den[8] once (reused for both tiles) ----
    float den[8];
    if (bi < 6) {
        const int ch = (sb < 16) ? 0 : ((sb < 20) ? 1 : 2);
        float q[8];
        *(float4*)&q[0] = *(const float4*)&smem[QNT + ch * 64 + lc * 8];
        *(float4*)&q[4] = *(const float4*)&smem[QNT + ch * 64 + lc * 8 + 4];
        const float qadd = (float)(0.5 / 255.0);
        #pragma unroll
        for (int cc = 0; cc < 8; ++cc)
            den[cc] = __fadd_rn(__fmul_rn(q[cc], 2.5f), qadd);  // no FMA contraction
    }

    // ---- DCT A (+ stores A) while B loads are outstanding ----
    if (bi < 6) dct_tile(smem, out, YTT0, CBT0, CRT0, tmpbase, den, b, th, twA, sb, lc);

    // ---- color B (waits on B loads), then DCT B ----
    color_store(vb, smem, YTT1, CBT1, CRT1, qr, qc);
    __syncthreads();
    if (bi < 6) dct_tile(smem, out, YTT1, CBT1, CRT1, tmpbase, den, b, th, twB, sb, lc);
}

extern "C" void kernel_launch(void* const* d_in, const int* in_sizes, int n_in,
                              void* d_out, int out_size, void* d_ws, size_t ws_size,
                              hipStream_t stream) {
    const float* rgb   = (const float*)d_in[0];
    const float* quant = (const float*)d_in[1];
    float* out = (float*)d_out;
    dim3 grid(2048), block(256);
    hipLaunchKernelGGL(jpeg_kernel, grid, block, 0, stream, rgb, quant, out);
}